// Round 8
// baseline (26.105 us; speedup 1.0000x reference)
//
#include <hip/hip_runtime.h>

// Post_process_deconv: out = depth + b + sum_k w[k] * (weight[k] - mean_k(weight)) *
//                           bilinear(depth, y - 1 + kh + dy_k, x - 1 + kw + dx_k)
// Shapes: depth [B,1,H,W], weight [B,9,H,W], offset [B,18,H,W], w [1,1,3,3], b [1]
// B=2, H=352, W=1216, K=3, pad=1. All fp32.
//
// Round 8: round-6 structure (1 px/thread, 64x4 tile + halo staged in LDS,
// zero-filled outside the image) with a BRANCH-FREE main loop: every tap's
// LDS read uses tile-clamped coordinates (provably in-bounds -> compiler can
// issue all 18 ds_read2 back-to-back, ILP hides LDS latency). Taps that are
// inside the image but outside the +-6 halo (P ~ 1e-8 for N(0,1) offsets,
// but handled exactly) set a miss bit; ONE per-pixel branch afterwards
// corrects those taps via global loads: acc += coeff * (s_true - s_fast).

#define KK 3
#define K2 9
#define PAD 1
#define BB 2
#define HH 352
#define WW 1216

#define TX 64                       // tile width  (19 tiles)
#define TY 4                        // tile height (88 tiles)
#define NTX (WW / TX)
#define NTY (HH / TY)
#define HALO 7
#define SROWS (TY + 2 * HALO + 1)   // 19
#define SCOLS (TX + 2 * HALO + 2)   // 80

__global__ __launch_bounds__(256) void ppd_kernel(
    const float* __restrict__ depth,   // [B, H*W]
    const float* __restrict__ weight,  // [B, 9, H*W]
    const float* __restrict__ offset,  // [B, 18, H*W]
    const float* __restrict__ wk,      // [9]
    const float* __restrict__ bias,    // [1]
    float* __restrict__ out)           // [B, H*W]
{
    constexpr int HW = HH * WW;

    __shared__ float sd[SROWS * SCOLS];   // 6080 B

    const int bid = blockIdx.x;
    const int b   = bid / (NTY * NTX);
    const int rem = bid - b * (NTY * NTX);
    const int ty  = rem / NTX;
    const int tx  = rem - ty * NTX;

    const int tid = threadIdx.x;
    const int lx  = tid & (TX - 1);
    const int lyq = tid >> 6;             // 0..3
    const int x   = tx * TX + lx;
    const int y   = ty * TY + lyq;

    const float* dimg = depth + (size_t)b * HW;
    const int base_y = ty * TY - HALO;
    const int base_x = tx * TX - HALO;

    // ---- stage depth tile into LDS (zero-filled outside image) ----
    for (int t = tid; t < SROWS * SCOLS; t += 256) {
        const int r  = t / SCOLS;
        const int c  = t - r * SCOLS;
        const int gy = base_y + r;
        const int gx = base_x + c;
        float v = 0.f;
        if ((unsigned)gy < (unsigned)HH && (unsigned)gx < (unsigned)WW)
            v = dimg[gy * WW + gx];
        sd[t] = v;
    }

    // ---- streaming plane loads (coalesced) ----
    const int hw = y * WW + x;
    const float* wgt = weight + (size_t)b * (K2 * HW) + hw;
    const float* off = offset + (size_t)b * (2 * K2 * HW) + hw;

    float wv[K2], dyv[K2], dxv[K2];
#pragma unroll
    for (int k = 0; k < K2; ++k) wv[k] = wgt[k * HW];
#pragma unroll
    for (int k = 0; k < K2; ++k) {
        dyv[k] = off[(2 * k)     * HW];
        dxv[k] = off[(2 * k + 1) * HW];
    }

    float wsum = 0.f;
#pragma unroll
    for (int k = 0; k < K2; ++k) wsum += wv[k];
    const float wmean = wsum * (1.0f / 9.0f);

    __syncthreads();

    // ---- branch-free main loop: clamped LDS reads, miss-bit bookkeeping ----
    float acc = 0.f;
    unsigned miss = 0u;
#pragma unroll
    for (int k = 0; k < K2; ++k) {
        const int kh = k / KK;
        const int kw = k - kh * KK;
        const float py = (float)(y - PAD + kh) + dyv[k];
        const float px = (float)(x - PAD + kw) + dxv[k];

        const float y0f = floorf(py);
        const float x0f = floorf(px);
        const float fy = py - y0f;
        const float fx = px - x0f;
        const int y0 = (int)y0f;
        const int x0 = (int)x0f;

        const int lr = y0 - base_y;
        const int lc = x0 - base_x;
        const int lrc = min(max(lr, 0), SROWS - 2);
        const int lcc = min(max(lc, 0), SCOLS - 2);
        const bool ok = ((unsigned)lr <= (unsigned)(SROWS - 2)) &
                        ((unsigned)lc <= (unsigned)(SCOLS - 2));

        const float* r0 = &sd[lrc * SCOLS + lcc];
        const float v00 = r0[0];
        const float v01 = r0[1];
        const float v10 = r0[SCOLS];
        const float v11 = r0[SCOLS + 1];
        const float s = (1.f - fy) * ((1.f - fx) * v00 + fx * v01)
                      + fy         * ((1.f - fx) * v10 + fx * v11);

        miss |= ok ? 0u : (1u << k);
        acc = fmaf(wk[k] * (wv[k] - wmean), s, acc);
    }

    // ---- rare exact fixup for taps outside the staged halo ----
    if (miss) {
#pragma unroll 1
        for (int k = 0; k < K2; ++k) {
            if (!(miss & (1u << k))) continue;
            const int kh = k / KK;
            const int kw = k - kh * KK;
            const float py = (float)(y - PAD + kh) + dyv[k];
            const float px = (float)(x - PAD + kw) + dxv[k];
            const float y0f = floorf(py);
            const float x0f = floorf(px);
            const float fy = py - y0f;
            const float fx = px - x0f;
            const int y0 = (int)y0f;
            const int x0 = (int)x0f;

            // recompute the (wrong) fast-path sample exactly as above
            const int lrc = min(max(y0 - base_y, 0), SROWS - 2);
            const int lcc = min(max(x0 - base_x, 0), SCOLS - 2);
            const float* r0 = &sd[lrc * SCOLS + lcc];
            const float sf = (1.f - fy) * ((1.f - fx) * r0[0] + fx * r0[1])
                           + fy         * ((1.f - fx) * r0[SCOLS] + fx * r0[SCOLS + 1]);

            // true sample via global clamped loads + validity-folded weights
            const float wy0 = ((unsigned)y0       < (unsigned)HH) ? (1.f - fy) : 0.f;
            const float wy1 = ((unsigned)(y0 + 1) < (unsigned)HH) ? fy         : 0.f;
            const float wx0 = ((unsigned)x0       < (unsigned)WW) ? (1.f - fx) : 0.f;
            const float wx1 = ((unsigned)(x0 + 1) < (unsigned)WW) ? fx         : 0.f;
            const int y0c = min(max(y0, 0), HH - 1);
            const int y1c = min(max(y0 + 1, 0), HH - 1);
            const int x0c = min(max(x0, 0), WW - 1);
            const int x1c = min(max(x0 + 1, 0), WW - 1);
            const float st = wy0 * (wx0 * dimg[y0c * WW + x0c] + wx1 * dimg[y0c * WW + x1c])
                           + wy1 * (wx0 * dimg[y1c * WW + x0c] + wx1 * dimg[y1c * WW + x1c]);

            acc = fmaf(wk[k] * (wv[k] - wmean), st - sf, acc);
        }
    }

    // residual from LDS; epilogue
    const float dres = sd[(y - base_y) * SCOLS + (x - base_x)];
    out[(size_t)b * HW + hw] = acc + bias[0] + dres;
}

extern "C" void kernel_launch(void* const* d_in, const int* in_sizes, int n_in,
                              void* d_out, int out_size, void* d_ws, size_t ws_size,
                              hipStream_t stream) {
    const float* depth  = (const float*)d_in[0];
    const float* weight = (const float*)d_in[1];
    const float* offset = (const float*)d_in[2];
    const float* wk     = (const float*)d_in[3];
    const float* bias   = (const float*)d_in[4];
    float* out = (float*)d_out;

    const int grid = BB * NTY * NTX;   // 3344
    ppd_kernel<<<grid, 256, 0, stream>>>(depth, weight, offset, wk, bias, out);
}

// Round 9
// 24.295 us; speedup vs baseline: 1.0745x; 1.0745x over previous
//
#include <hip/hip_runtime.h>

// Post_process_deconv: out = depth + b + sum_k w[k] * (weight[k] - mean_k(weight)) *
//                           bilinear(depth, y - 1 + kh + dy_k, x - 1 + kw + dx_k)
// Shapes: depth [B,1,H,W], weight [B,9,H,W], offset [B,18,H,W], w [1,1,3,3], b [1]
// B=2, H=352, W=1216, K=3, pad=1. All fp32.
//
// Round 9: same structure as r8 (64x4 tile + halo in LDS, zero-filled OOB,
// branchless clamped-LDS taps + rare exact fixup), but fix the register
// starvation that serialized every memory phase:
//   (a) __launch_bounds__(256, 4): VGPR budget 128 (was 40 at default) so all
//       27 streaming loads + 36 tap ds_reads can be in flight at once;
//   (b) staging phase-split: 6 global loads -> regs (one vmcnt wait), then
//       6 ds_writes, then barrier (was 6x load-wait-write round trips).

#define KK 3
#define K2 9
#define PAD 1
#define BB 2
#define HH 352
#define WW 1216

#define TX 64                       // tile width  (19 tiles)
#define TY 4                        // tile height (88 tiles)
#define NTX (WW / TX)
#define NTY (HH / TY)
#define HALO 7
#define SROWS (TY + 2 * HALO + 1)   // 19
#define SCOLS (TX + 2 * HALO + 2)   // 80
#define SN (SROWS * SCOLS)          // 1520
#define NSTG ((SN + 255) / 256)     // 6

__global__ __launch_bounds__(256, 4) void ppd_kernel(
    const float* __restrict__ depth,   // [B, H*W]
    const float* __restrict__ weight,  // [B, 9, H*W]
    const float* __restrict__ offset,  // [B, 18, H*W]
    const float* __restrict__ wk,      // [9]
    const float* __restrict__ bias,    // [1]
    float* __restrict__ out)           // [B, H*W]
{
    constexpr int HW = HH * WW;

    __shared__ float sd[SN];            // 6080 B

    const int bid = blockIdx.x;
    const int b   = bid / (NTY * NTX);
    const int rem = bid - b * (NTY * NTX);
    const int ty  = rem / NTX;
    const int tx  = rem - ty * NTX;

    const int tid = threadIdx.x;
    const int lx  = tid & (TX - 1);
    const int lyq = tid >> 6;             // 0..3
    const int x   = tx * TX + lx;
    const int y   = ty * TY + lyq;

    const float* dimg = depth + (size_t)b * HW;
    const int base_y = ty * TY - HALO;
    const int base_x = tx * TX - HALO;

    // ---- staging phase A: all global loads to registers (one wait) ----
    float stg[NSTG];
#pragma unroll
    for (int i = 0; i < NSTG; ++i) {
        const int t = tid + i * 256;
        const int r = t / SCOLS;
        const int c = t - r * SCOLS;
        const int gy = base_y + r;
        const int gx = base_x + c;
        float v = 0.f;
        if (t < SN && (unsigned)gy < (unsigned)HH && (unsigned)gx < (unsigned)WW)
            v = dimg[gy * WW + gx];
        stg[i] = v;
    }

    // ---- streaming plane loads (independent; issue alongside staging) ----
    const int hw = y * WW + x;
    const float* wgt = weight + (size_t)b * (K2 * HW) + hw;
    const float* off = offset + (size_t)b * (2 * K2 * HW) + hw;

    float wv[K2], dyv[K2], dxv[K2];
#pragma unroll
    for (int k = 0; k < K2; ++k) wv[k] = wgt[k * HW];
#pragma unroll
    for (int k = 0; k < K2; ++k) {
        dyv[k] = off[(2 * k)     * HW];
        dxv[k] = off[(2 * k + 1) * HW];
    }

    // ---- staging phase B: LDS writes, then barrier ----
#pragma unroll
    for (int i = 0; i < NSTG; ++i) {
        const int t = tid + i * 256;
        if (t < SN) sd[t] = stg[i];
    }

    float wsum = 0.f;
#pragma unroll
    for (int k = 0; k < K2; ++k) wsum += wv[k];
    const float wmean = wsum * (1.0f / 9.0f);

    __syncthreads();

    // ---- branchless main loop: clamped LDS reads, miss-bit bookkeeping ----
    float acc = 0.f;
    unsigned miss = 0u;
#pragma unroll
    for (int k = 0; k < K2; ++k) {
        const int kh = k / KK;
        const int kw = k - kh * KK;
        const float py = (float)(y - PAD + kh) + dyv[k];
        const float px = (float)(x - PAD + kw) + dxv[k];

        const float y0f = floorf(py);
        const float x0f = floorf(px);
        const float fy = py - y0f;
        const float fx = px - x0f;
        const int y0 = (int)y0f;
        const int x0 = (int)x0f;

        const int lr = y0 - base_y;
        const int lc = x0 - base_x;
        const int lrc = min(max(lr, 0), SROWS - 2);
        const int lcc = min(max(lc, 0), SCOLS - 2);
        const bool ok = ((unsigned)lr <= (unsigned)(SROWS - 2)) &
                        ((unsigned)lc <= (unsigned)(SCOLS - 2));

        const float* r0 = &sd[lrc * SCOLS + lcc];
        const float v00 = r0[0];
        const float v01 = r0[1];
        const float v10 = r0[SCOLS];
        const float v11 = r0[SCOLS + 1];
        const float s = (1.f - fy) * ((1.f - fx) * v00 + fx * v01)
                      + fy         * ((1.f - fx) * v10 + fx * v11);

        miss |= ok ? 0u : (1u << k);
        acc = fmaf(wk[k] * (wv[k] - wmean), s, acc);
    }

    // ---- rare exact fixup for taps outside the staged halo ----
    if (miss) {
#pragma unroll 1
        for (int k = 0; k < K2; ++k) {
            if (!(miss & (1u << k))) continue;
            const int kh = k / KK;
            const int kw = k - kh * KK;
            const float py = (float)(y - PAD + kh) + dyv[k];
            const float px = (float)(x - PAD + kw) + dxv[k];
            const float y0f = floorf(py);
            const float x0f = floorf(px);
            const float fy = py - y0f;
            const float fx = px - x0f;
            const int y0 = (int)y0f;
            const int x0 = (int)x0f;

            // recompute the (wrong) fast-path sample exactly as above
            const int lrc = min(max(y0 - base_y, 0), SROWS - 2);
            const int lcc = min(max(x0 - base_x, 0), SCOLS - 2);
            const float* r0 = &sd[lrc * SCOLS + lcc];
            const float sf = (1.f - fy) * ((1.f - fx) * r0[0] + fx * r0[1])
                           + fy         * ((1.f - fx) * r0[SCOLS] + fx * r0[SCOLS + 1]);

            // true sample via global clamped loads + validity-folded weights
            const float wy0 = ((unsigned)y0       < (unsigned)HH) ? (1.f - fy) : 0.f;
            const float wy1 = ((unsigned)(y0 + 1) < (unsigned)HH) ? fy         : 0.f;
            const float wx0 = ((unsigned)x0       < (unsigned)WW) ? (1.f - fx) : 0.f;
            const float wx1 = ((unsigned)(x0 + 1) < (unsigned)WW) ? fx         : 0.f;
            const int y0c = min(max(y0, 0), HH - 1);
            const int y1c = min(max(y0 + 1, 0), HH - 1);
            const int x0c = min(max(x0, 0), WW - 1);
            const int x1c = min(max(x0 + 1, 0), WW - 1);
            const float st = wy0 * (wx0 * dimg[y0c * WW + x0c] + wx1 * dimg[y0c * WW + x1c])
                           + wy1 * (wx0 * dimg[y1c * WW + x0c] + wx1 * dimg[y1c * WW + x1c]);

            acc = fmaf(wk[k] * (wv[k] - wmean), st - sf, acc);
        }
    }

    // residual from LDS; epilogue
    const float dres = sd[(y - base_y) * SCOLS + (x - base_x)];
    out[(size_t)b * HW + hw] = acc + bias[0] + dres;
}

extern "C" void kernel_launch(void* const* d_in, const int* in_sizes, int n_in,
                              void* d_out, int out_size, void* d_ws, size_t ws_size,
                              hipStream_t stream) {
    const float* depth  = (const float*)d_in[0];
    const float* weight = (const float*)d_in[1];
    const float* offset = (const float*)d_in[2];
    const float* wk     = (const float*)d_in[3];
    const float* bias   = (const float*)d_in[4];
    float* out = (float*)d_out;

    const int grid = BB * NTY * NTX;   // 3344
    ppd_kernel<<<grid, 256, 0, stream>>>(depth, weight, offset, wk, bias, out);
}

// Round 10
// 23.522 us; speedup vs baseline: 1.1098x; 1.0329x over previous
//
#include <hip/hip_runtime.h>

// Post_process_deconv: out = depth + b + sum_k w[k] * (weight[k] - mean_k(weight)) *
//                           bilinear(depth, y - 1 + kh + dy_k, x - 1 + kw + dx_k)
// Shapes: depth [B,1,H,W], weight [B,9,H,W], offset [B,18,H,W], w [1,1,3,3], b [1]
// B=2, H=352, W=1216, K=3, pad=1. All fp32.
//
// Round 10: LDS tile packed as ROW PAIRS pd[r][c] = (d[r][c], d[r+1][c])
// (float2): one tap = two adjacent 8B entries -> one ds_read2_b64 delivers
// all 4 bilinear corners (was 2 insts / 4 bank accesses). Tap loop is phase-
// split: (1) all 9 addresses+fracs (VALU), (2) all 9 corner reads issued
// back-to-back (one lgkm wait covers the pipelined batch), (3) all lerps+FMAs.
// Zero-filled OOB entries keep zero-outside semantics free; rare taps outside
// the +-7 halo get an exact global fixup after the loop.

#define KK 3
#define K2 9
#define PAD 1
#define BB 2
#define HH 352
#define WW 1216

#define TX 64                       // tile width  (19 tiles)
#define TY 4                        // tile height (88 tiles)
#define NTX (WW / TX)
#define NTY (HH / TY)
#define HALO 7
#define SROWS (TY + 2 * HALO + 1)   // 19 raw rows
#define PROWS (SROWS - 1)           // 18 packed row-pair rows
#define SCOLS (TX + 2 * HALO + 2)   // 80
#define PN (PROWS * SCOLS)          // 1440 packed entries
#define NSTG ((PN + 255) / 256)     // 6

__global__ __launch_bounds__(256, 4) void ppd_kernel(
    const float* __restrict__ depth,   // [B, H*W]
    const float* __restrict__ weight,  // [B, 9, H*W]
    const float* __restrict__ offset,  // [B, 18, H*W]
    const float* __restrict__ wk,      // [9]
    const float* __restrict__ bias,    // [1]
    float* __restrict__ out)           // [B, H*W]
{
    constexpr int HW = HH * WW;

    __shared__ float2 pd[PN];           // 11520 B

    const int bid = blockIdx.x;
    const int b   = bid / (NTY * NTX);
    const int rem = bid - b * (NTY * NTX);
    const int ty  = rem / NTX;
    const int tx  = rem - ty * NTX;

    const int tid = threadIdx.x;
    const int lx  = tid & (TX - 1);
    const int lyq = tid >> 6;             // 0..3
    const int x   = tx * TX + lx;
    const int y   = ty * TY + lyq;

    const float* dimg = depth + (size_t)b * HW;
    const int base_y = ty * TY - HALO;
    const int base_x = tx * TX - HALO;

    // ---- staging phase A: all global loads to registers (pairs) ----
    float2 stg[NSTG];
#pragma unroll
    for (int i = 0; i < NSTG; ++i) {
        const int t = tid + i * 256;
        const int r = t / SCOLS;
        const int c = t - r * SCOLS;
        const int gy = base_y + r;
        const int gx = base_x + c;
        float a = 0.f, bb2 = 0.f;
        const bool gxok = ((unsigned)gx < (unsigned)WW) && (t < PN);
        if (gxok && (unsigned)gy < (unsigned)HH)       a   = dimg[gy * WW + gx];
        if (gxok && (unsigned)(gy + 1) < (unsigned)HH) bb2 = dimg[(gy + 1) * WW + gx];
        stg[i] = make_float2(a, bb2);
    }

    // ---- streaming plane loads (independent; stay in flight) ----
    const int hw = y * WW + x;
    const float* wgt = weight + (size_t)b * (K2 * HW) + hw;
    const float* off = offset + (size_t)b * (2 * K2 * HW) + hw;

    float dyv[K2], dxv[K2], wv[K2];
#pragma unroll
    for (int k = 0; k < K2; ++k) {
        dyv[k] = off[(2 * k)     * HW];
        dxv[k] = off[(2 * k + 1) * HW];
    }
#pragma unroll
    for (int k = 0; k < K2; ++k) wv[k] = wgt[k * HW];

    // ---- staging phase B: LDS writes, then barrier ----
#pragma unroll
    for (int i = 0; i < NSTG; ++i) {
        const int t = tid + i * 256;
        if (t < PN) pd[t] = stg[i];
    }
    __syncthreads();

    // ---- tap phase 1: all addresses + fracs + miss bits (pure VALU) ----
    int   ta[K2];
    float fyv[K2], fxv[K2];
    unsigned miss = 0u;
#pragma unroll
    for (int k = 0; k < K2; ++k) {
        const int kh = k / KK;
        const int kw = k - kh * KK;
        const float py = (float)(y - PAD + kh) + dyv[k];
        const float px = (float)(x - PAD + kw) + dxv[k];
        const float y0f = floorf(py);
        const float x0f = floorf(px);
        fyv[k] = py - y0f;
        fxv[k] = px - x0f;
        const int y0 = (int)y0f;
        const int x0 = (int)x0f;
        const int lr = y0 - base_y;
        const int lc = x0 - base_x;
        const int lrc = min(max(lr, 0), PROWS - 1);
        const int lcc = min(max(lc, 0), SCOLS - 2);
        const bool ok = ((unsigned)lr <= (unsigned)(PROWS - 1)) &
                        ((unsigned)lc <= (unsigned)(SCOLS - 2));
        miss |= ok ? 0u : (1u << k);
        ta[k] = lrc * SCOLS + lcc;
    }

    // ---- tap phase 2: all corner-pair reads, issued back-to-back ----
    float2 c0[K2], c1[K2];
#pragma unroll
    for (int k = 0; k < K2; ++k) {
        c0[k] = pd[ta[k]];          // (v00, v10)
        c1[k] = pd[ta[k] + 1];      // (v01, v11)
    }

    // ---- mean of weights (streams have arrived by now) ----
    float wsum = 0.f;
#pragma unroll
    for (int k = 0; k < K2; ++k) wsum += wv[k];
    const float wmean = wsum * (1.0f / 9.0f);

    // ---- tap phase 3: all lerps + FMAs (pure VALU) ----
    float acc = 0.f;
#pragma unroll
    for (int k = 0; k < K2; ++k) {
        const float fy = fyv[k];
        const float fx = fxv[k];
        const float s = (1.f - fy) * ((1.f - fx) * c0[k].x + fx * c1[k].x)
                      + fy         * ((1.f - fx) * c0[k].y + fx * c1[k].y);
        acc = fmaf(wk[k] * (wv[k] - wmean), s, acc);
    }

    // ---- rare exact fixup for taps outside the staged halo ----
    if (miss) {
#pragma unroll 1
        for (int k = 0; k < K2; ++k) {
            if (!(miss & (1u << k))) continue;
            const int kh = k / KK;
            const int kw = k - kh * KK;
            const float py = (float)(y - PAD + kh) + dyv[k];
            const float px = (float)(x - PAD + kw) + dxv[k];
            const float y0f = floorf(py);
            const float x0f = floorf(px);
            const float fy = py - y0f;
            const float fx = px - x0f;
            const int y0 = (int)y0f;
            const int x0 = (int)x0f;

            // recompute the (wrong) fast-path sample exactly as above
            const int lrc = min(max(y0 - base_y, 0), PROWS - 1);
            const int lcc = min(max(x0 - base_x, 0), SCOLS - 2);
            const float2 e0 = pd[lrc * SCOLS + lcc];
            const float2 e1 = pd[lrc * SCOLS + lcc + 1];
            const float sf = (1.f - fy) * ((1.f - fx) * e0.x + fx * e1.x)
                           + fy         * ((1.f - fx) * e0.y + fx * e1.y);

            // true sample via global clamped loads + validity-folded weights
            const float wy0 = ((unsigned)y0       < (unsigned)HH) ? (1.f - fy) : 0.f;
            const float wy1 = ((unsigned)(y0 + 1) < (unsigned)HH) ? fy         : 0.f;
            const float wx0 = ((unsigned)x0       < (unsigned)WW) ? (1.f - fx) : 0.f;
            const float wx1 = ((unsigned)(x0 + 1) < (unsigned)WW) ? fx         : 0.f;
            const int y0c = min(max(y0, 0), HH - 1);
            const int y1c = min(max(y0 + 1, 0), HH - 1);
            const int x0c = min(max(x0, 0), WW - 1);
            const int x1c = min(max(x0 + 1, 0), WW - 1);
            const float st = wy0 * (wx0 * dimg[y0c * WW + x0c] + wx1 * dimg[y0c * WW + x1c])
                           + wy1 * (wx0 * dimg[y1c * WW + x0c] + wx1 * dimg[y1c * WW + x1c]);

            acc = fmaf(wk[k] * (wv[k] - wmean), st - sf, acc);
        }
    }

    // residual from LDS; epilogue
    const float dres = pd[(y - base_y) * SCOLS + (x - base_x)].x;
    out[(size_t)b * HW + hw] = acc + bias[0] + dres;
}

extern "C" void kernel_launch(void* const* d_in, const int* in_sizes, int n_in,
                              void* d_out, int out_size, void* d_ws, size_t ws_size,
                              hipStream_t stream) {
    const float* depth  = (const float*)d_in[0];
    const float* weight = (const float*)d_in[1];
    const float* offset = (const float*)d_in[2];
    const float* wk     = (const float*)d_in[3];
    const float* bias   = (const float*)d_in[4];
    float* out = (float*)d_out;

    const int grid = BB * NTY * NTX;   // 3344
    ppd_kernel<<<grid, 256, 0, stream>>>(depth, weight, offset, wk, bias, out);
}